// Round 1
// baseline (1205.255 us; speedup 1.0000x reference)
//
#include <hip/hip_runtime.h>
#include <hip/hip_fp16.h>

// ============================================================================
// 2-layer LSTM (B=16384, T=128, F=12, H1=64, H2=128) + linear head.
// Strategy: fp16 MFMA (16x16x32) for all gate matmuls, fp32 accumulate,
// fp32 nonlinearities and cell state. Weights pre-packed once per call into
// MFMA B-fragments in d_ws (prep kernel), then held in VGPRs for the whole
// T-loop (471KB fp32 weights cannot live in LDS; L2-streaming would cost
// ~15TB). Block = 512 threads (8 waves) owns 16 batch rows; 1024 blocks.
//
// Fragment layout assumptions (verified in learn_hip m89/m91/m92 for this
// shape): A: row=l&15, k=(l>>4)*8+j (8 contiguous k); B: col=l&15, same k;
// C/D: col=l&15, row=(l>>4)*4+j.  If absmax is O(1e-1), suspect these.
// If absmax is ~1e-3, switch to W-split 2-pass fp16.
// ============================================================================

#define T_STEPS 128
#define F_IN    12
#define R       16      // batch rows per block
#define S0      104     // state0 stride (halves): [x(12)|h0(64)|zeros(20)|pad(8)] ; 208B = 13*16B (odd)
#define S1      200     // state1 stride (halves): [h0(64)|h1(128)|pad(8)] ; 400B = 25*16B (odd)
#define SB      516     // shared sigma-buffer stride (floats), aliased between layer0/layer1 phases

#define WF0_H8  (16*3*64)            // 3072 half8 fragments, layer0 (16 coltiles x 3 ktiles)
#define WF1_H8  (32*6*64)            // 12288 half8 fragments, layer1 (32 coltiles x 6 ktiles)
#define WH_TOTAL_HALVES ((WF0_H8 + WF1_H8)*8)   // 122880 halves = 245760 B

typedef _Float16 half8 __attribute__((ext_vector_type(8)));
typedef float   floatx4 __attribute__((ext_vector_type(4)));

__device__ __forceinline__ float fexp2(float x){
#if __has_builtin(__builtin_amdgcn_exp2f)
  return __builtin_amdgcn_exp2f(x);
#else
  return exp2f(x);
#endif
}
__device__ __forceinline__ float frcp(float x){
#if __has_builtin(__builtin_amdgcn_rcpf)
  return __builtin_amdgcn_rcpf(x);
#else
  return 1.0f / x;
#endif
}
__device__ __forceinline__ float fast_sig(float x){
  // sigmoid(x) = 1/(1+2^(-x*log2e)) ; saturates correctly at +-inf
  return frcp(1.0f + fexp2(-1.4426950408889634f * x));
}
__device__ __forceinline__ float fast_tanh(float x){
  // tanh(x) = 1 - 2/(2^(2x*log2e)+1)
  return 1.0f - 2.0f * frcp(fexp2(2.8853900817779268f * x) + 1.0f);
}

// ---------------------------------------------------------------------------
// Prep: pack fp16 MFMA B-fragments + fused biases into d_ws.
//   wfrag0[ct][kt][lane] : W0cat[col=ct*16+(l&15)][k=kt*32+(l>>4)*8+j], k<12 from W_ih0, 12..75 from W_hh0, else 0
//   wfrag1[ct][kt][lane] : W1cat[col][k], k<64 from W_ih1, else W_hh1[k-64]
//   bsum0[256], bsum1[512] floats after the halves region.
// ---------------------------------------------------------------------------
__global__ void prep_kernel(const float* __restrict__ Wih0, const float* __restrict__ Whh0,
                            const float* __restrict__ bih0, const float* __restrict__ bhh0,
                            const float* __restrict__ Wih1, const float* __restrict__ Whh1,
                            const float* __restrict__ bih1, const float* __restrict__ bhh1,
                            _Float16* __restrict__ wh, float* __restrict__ bs) {
  int tid = blockIdx.x * 256 + threadIdx.x;
  if (tid < WF0_H8) {
    int lane = tid & 63; int kt = (tid >> 6) % 3; int ct = tid / (64*3);
    int col = ct*16 + (lane & 15);
    int kbase = kt*32 + (lane >> 4)*8;
    #pragma unroll
    for (int j = 0; j < 8; ++j) {
      int k = kbase + j; float w = 0.0f;
      if (k < 12) w = Wih0[col*12 + k];
      else if (k < 76) w = Whh0[col*64 + (k-12)];
      wh[tid*8 + j] = (_Float16)w;
    }
  } else if (tid < WF0_H8 + WF1_H8) {
    int t2 = tid - WF0_H8;
    int lane = t2 & 63; int kt = (t2 >> 6) % 6; int ct = t2 / (64*6);
    int col = ct*16 + (lane & 15);
    int kbase = kt*32 + (lane >> 4)*8;
    #pragma unroll
    for (int j = 0; j < 8; ++j) {
      int k = kbase + j;
      float w = (k < 64) ? Wih1[col*64 + k] : Whh1[col*128 + (k-64)];
      wh[WF0_H8*8 + t2*8 + j] = (_Float16)w;
    }
  } else if (tid < WF0_H8 + WF1_H8 + 768) {
    int t3 = tid - (WF0_H8 + WF1_H8);
    if (t3 < 256) bs[t3] = bih0[t3] + bhh0[t3];
    else          bs[t3] = bih1[t3-256] + bhh1[t3-256];
  }
}

// ---------------------------------------------------------------------------
// Main kernel. 512 threads (8 waves), 16 rows/block, 1024 blocks.
// Per wave: gates0 coltiles {2w,2w+1} (16 cols each), gates1 coltiles {4w..4w+3}.
// Weight frags live in VGPRs across the whole T loop (~120 VGPRs).
// ---------------------------------------------------------------------------
__global__ __launch_bounds__(512, 2)
void lstm_kernel(const float* __restrict__ x, const _Float16* __restrict__ wh,
                 const float* __restrict__ bs,
                 const float* __restrict__ Wd1, const float* __restrict__ bd1,
                 const float* __restrict__ Wd2, const float* __restrict__ bd2,
                 float* __restrict__ out) {
  __shared__ _Float16 st0[R][S0];     // 3328 B
  __shared__ _Float16 st1[R][S1];     // 6400 B
  __shared__ float    sbuf[R][SB];    // 33024 B (aliased: gates0 sigma / gates1 sigma / final h1 stash)
  __shared__ float    c0s[R][64];     // 4096 B
  __shared__ float    c1s[R][128];    // 8192 B
  __shared__ float    redbuf[R][32];  // 2048 B   -> total ~57 KB

  const int tid  = threadIdx.x;
  const int wv   = tid >> 6;
  const int lane = tid & 63;
  const int l15  = lane & 15;
  const int lg   = lane >> 4;          // 0..3
  const int rowbase = blockIdx.x * R;

  // ---- load weight fragments into registers (stay live across T loop) ----
  const half8* whv = (const half8*)wh;
  half8 wb0[2][3];
  half8 wb1[4][6];
  #pragma unroll
  for (int i = 0; i < 2; ++i) {
    int ct = wv*2 + i;
    #pragma unroll
    for (int kt = 0; kt < 3; ++kt) wb0[i][kt] = whv[(ct*3 + kt)*64 + lane];
  }
  #pragma unroll
  for (int i = 0; i < 4; ++i) {
    int ct = wv*4 + i;
    #pragma unroll
    for (int kt = 0; kt < 6; ++kt) wb1[i][kt] = whv[WF0_H8 + (ct*6 + kt)*64 + lane];
  }
  float bias0[2], bias1[4];
  #pragma unroll
  for (int i = 0; i < 2; ++i) bias0[i] = bs[(wv*2 + i)*16 + l15];
  #pragma unroll
  for (int i = 0; i < 4; ++i) bias1[i] = bs[256 + (wv*4 + i)*16 + l15];

  // ---- init LDS state to zero ----
  for (int idx = tid; idx < R*S0; idx += 512) ((_Float16*)st0)[idx] = (_Float16)0.0f;
  for (int idx = tid; idx < R*S1; idx += 512) ((_Float16*)st1)[idx] = (_Float16)0.0f;
  for (int idx = tid; idx < R*64;  idx += 512) ((float*)c0s)[idx] = 0.0f;
  for (int idx = tid; idx < R*128; idx += 512) ((float*)c1s)[idx] = 0.0f;
  __syncthreads();
  // load x(t=0)
  int xr = 0, xf = 0;
  if (tid < R*F_IN) {
    xr = tid / F_IN; xf = tid % F_IN;
    st0[xr][xf] = (_Float16)x[((size_t)(rowbase + xr)*T_STEPS + 0)*F_IN + xf];
  }
  __syncthreads();

  float xpre = 0.0f;

  for (int t = 0; t < T_STEPS; ++t) {
    // ---------------- Phase A: gates0 = [x|h0] @ W0cat^T, sigma in-register ----------------
    {
      half8 a[3];
      #pragma unroll
      for (int kt = 0; kt < 3; ++kt)
        a[kt] = *(const half8*)&st0[l15][kt*32 + lg*8];
      #pragma unroll
      for (int i = 0; i < 2; ++i) {
        const int ct = wv*2 + i;
        floatx4 acc = {bias0[i], bias0[i], bias0[i], bias0[i]};
        #pragma unroll
        for (int kt = 0; kt < 3; ++kt)
          acc = __builtin_amdgcn_mfma_f32_16x16x32_f16(a[kt], wb0[i][kt], acc, 0, 0, 0);
        const int gt = ct >> 2;   // 0:i 1:f 2:g 3:o  (tile-uniform)
        #pragma unroll
        for (int j = 0; j < 4; ++j) {
          float v = acc[j];
          float s = (gt == 2) ? fast_tanh(v) : fast_sig(v);
          sbuf[lg*4 + j][ct*16 + l15] = s;
        }
      }
    }
    __syncthreads();

    // ---------------- Phase B: cell0 update; issue x(t+1) prefetch ----------------
    {
      const int tnext = (t + 1 < T_STEPS) ? t + 1 : t;
      if (tid < R*F_IN) xpre = x[((size_t)(rowbase + xr)*T_STEPS + tnext)*F_IN + xf];
      #pragma unroll
      for (int p = 0; p < 2; ++p) {
        int id = tid + p*512;
        int r = id >> 6, j = id & 63;
        float iv = sbuf[r][j], fv = sbuf[r][64 + j], gv = sbuf[r][128 + j], ov = sbuf[r][192 + j];
        float c = fv * c0s[r][j] + iv * gv;
        c0s[r][j] = c;
        float h = ov * fast_tanh(c);
        _Float16 hh = (_Float16)h;
        st0[r][12 + j] = hh;   // feeds gates0(t+1)
        st1[r][j]      = hh;   // feeds gates1(t)
      }
    }
    __syncthreads();

    // ---------------- Phase C: gates1 = [h0|h1] @ W1cat^T ----------------
    {
      half8 a[6];
      #pragma unroll
      for (int kt = 0; kt < 6; ++kt)
        a[kt] = *(const half8*)&st1[l15][kt*32 + lg*8];
      #pragma unroll
      for (int i = 0; i < 4; ++i) {
        const int ct = wv*4 + i;
        floatx4 acc = {bias1[i], bias1[i], bias1[i], bias1[i]};
        #pragma unroll
        for (int kt = 0; kt < 6; ++kt)
          acc = __builtin_amdgcn_mfma_f32_16x16x32_f16(a[kt], wb1[i][kt], acc, 0, 0, 0);
        const int gt = ct >> 3;
        #pragma unroll
        for (int j = 0; j < 4; ++j) {
          float v = acc[j];
          float s = (gt == 2) ? fast_tanh(v) : fast_sig(v);
          sbuf[lg*4 + j][ct*16 + l15] = s;
        }
      }
    }
    __syncthreads();

    // ---------------- Phase D: cell1 update; write prefetched x ----------------
    {
      #pragma unroll
      for (int p = 0; p < 4; ++p) {
        int id = tid + p*512;
        int r = id >> 7, j = id & 127;
        float iv = sbuf[r][j], fv = sbuf[r][128 + j], gv = sbuf[r][256 + j], ov = sbuf[r][384 + j];
        float c = fv * c1s[r][j] + iv * gv;
        c1s[r][j] = c;
        float h = ov * fast_tanh(c);
        st1[r][64 + j] = (_Float16)h;            // feeds gates1(t+1)
        if (t == T_STEPS - 1) sbuf[r][j] = h;    // stash fp32 h1 for head (own i-slot, read-before-write)
      }
      if (tid < R*F_IN) st0[xr][xf] = (_Float16)xpre;
    }
    __syncthreads();
  }

  // ---------------- Head: out[r] = b_d2 + sum_j Wd2[j]*(b_d1[j] + sum_k Wd1[j][k]*h1[r][k]) ----------------
  {
    int r = tid & 15, jg = tid >> 4;   // 32 j-groups of 2
    float partial = 0.0f;
    #pragma unroll
    for (int jj = 0; jj < 2; ++jj) {
      int j = jg*2 + jj;
      float d = bd1[j];
      for (int k = 0; k < 128; ++k) d += Wd1[j*128 + k] * sbuf[r][k];
      partial += Wd2[j] * d;
    }
    redbuf[r][jg] = partial;
  }
  __syncthreads();
  if (tid < R) {
    float s = bd2[0];
    #pragma unroll
    for (int k = 0; k < 32; ++k) s += redbuf[tid][k];
    out[rowbase + tid] = s;
  }
}

extern "C" void kernel_launch(void* const* d_in, const int* in_sizes, int n_in,
                              void* d_out, int out_size, void* d_ws, size_t ws_size,
                              hipStream_t stream) {
  const float* x    = (const float*)d_in[0];
  const float* Wih0 = (const float*)d_in[1];
  const float* Whh0 = (const float*)d_in[2];
  const float* bih0 = (const float*)d_in[3];
  const float* bhh0 = (const float*)d_in[4];
  const float* Wih1 = (const float*)d_in[5];
  const float* Whh1 = (const float*)d_in[6];
  const float* bih1 = (const float*)d_in[7];
  const float* bhh1 = (const float*)d_in[8];
  const float* Wd1  = (const float*)d_in[9];
  const float* bd1  = (const float*)d_in[10];
  const float* Wd2  = (const float*)d_in[11];
  const float* bd2  = (const float*)d_in[12];
  float* out = (float*)d_out;

  _Float16* wh  = (_Float16*)d_ws;
  float*    bsv = (float*)((char*)d_ws + (size_t)WH_TOTAL_HALVES * 2);  // 245760 B offset

  // pack weight fragments + fused biases (16128 threads)
  prep_kernel<<<63, 256, 0, stream>>>(Wih0, Whh0, bih0, bhh0, Wih1, Whh1, bih1, bhh1, wh, bsv);

  // 16384 rows / 16 per block = 1024 blocks
  lstm_kernel<<<1024, 512, 0, stream>>>(x, wh, bsv, Wd1, bd1, Wd2, bd2, out);
}

// Round 3
// 1104.321 us; speedup vs baseline: 1.0914x; 1.0914x over previous
//
#include <hip/hip_runtime.h>
#include <hip/hip_fp16.h>

// ============================================================================
// 2-layer LSTM (B=16384, T=128, F=12, H1=64, H2=128) + head, round 3
// (round-2 design, compile fix: removed vestigial placeholder lambda).
//  - 16-wave blocks (1024 thr): weight frags 60 VGPR/wave -> register-resident
//    at the 4-waves/SIMD tier (R1's VGPR=104 < 120 proved non-residency).
//  - PERMUTED gate packing: weight col p = 4*hidden+gate, so one wave's C/D
//    tile holds all 4 gates of its hidden units -> cell update is wave-local
//    (1KB LDS scratch gather, no __syncthreads), cell state in registers.
//  - 2 barriers/timestep (was 4); sbuf/c0s/c1s eliminated.
//  - Unified nonlinearity z = am*sigma(sc*x)+bm (tanh = 2*sigma(2x)-1).
// ============================================================================

#define T_STEPS 128
#define F_IN    12
#define R       16      // batch rows per block
#define S0      104     // st0 row stride (halves): [x12|h0 64|zero20|pad8], 208B=13*16B
#define S1      328     // st1 row stride (halves): [h0 64|h1_p0 128|h1_p1 128|pad8], 656B=41*16B

#define WF0_H8  (16*3*64)
#define WF1_H8  (32*6*64)
#define WH_TOTAL_HALVES ((WF0_H8 + WF1_H8)*8)   // 245760 B

typedef _Float16 half8 __attribute__((ext_vector_type(8)));
typedef _Float16 half4 __attribute__((ext_vector_type(4)));
typedef float   floatx4 __attribute__((ext_vector_type(4)));

__device__ __forceinline__ float fexp2(float x){
#if __has_builtin(__builtin_amdgcn_exp2f)
  return __builtin_amdgcn_exp2f(x);
#else
  return exp2f(x);
#endif
}
__device__ __forceinline__ float frcp(float x){
#if __has_builtin(__builtin_amdgcn_rcpf)
  return __builtin_amdgcn_rcpf(x);
#else
  return 1.0f / x;
#endif
}
// Same-wave LDS RAW: DS pipe is in-order per wave; this stops the compiler
// from reordering the scratch write/read pair.
__device__ __forceinline__ void wavebar(){
  asm volatile("" ::: "memory");
  __builtin_amdgcn_wave_barrier();
  asm volatile("" ::: "memory");
}

// ---------------------------------------------------------------------------
// Prep: pack fp16 MFMA B-fragments (PERMUTED columns p=4h+g) + fused biases.
// ---------------------------------------------------------------------------
__global__ void prep_kernel(const float* __restrict__ Wih0, const float* __restrict__ Whh0,
                            const float* __restrict__ bih0, const float* __restrict__ bhh0,
                            const float* __restrict__ Wih1, const float* __restrict__ Whh1,
                            const float* __restrict__ bih1, const float* __restrict__ bhh1,
                            _Float16* __restrict__ wh, float* __restrict__ bs) {
  int tid = blockIdx.x * 256 + threadIdx.x;
  if (tid < WF0_H8) {
    int lane = tid & 63; int kt = (tid >> 6) % 3; int ct = tid / (64*3);
    int p = ct*16 + (lane & 15);
    int col = (p & 3)*64 + (p >> 2);          // orig row of W0cat: gate*64 + hidden
    int kbase = kt*32 + (lane >> 4)*8;
    #pragma unroll
    for (int j = 0; j < 8; ++j) {
      int k = kbase + j; float w = 0.0f;
      if (k < 12) w = Wih0[col*12 + k];
      else if (k < 76) w = Whh0[col*64 + (k-12)];
      wh[tid*8 + j] = (_Float16)w;
    }
  } else if (tid < WF0_H8 + WF1_H8) {
    int t2 = tid - WF0_H8;
    int lane = t2 & 63; int kt = (t2 >> 6) % 6; int ct = t2 / (64*6);
    int p = ct*16 + (lane & 15);
    int col = (p & 3)*128 + (p >> 2);         // gate*128 + hidden
    int kbase = kt*32 + (lane >> 4)*8;
    #pragma unroll
    for (int j = 0; j < 8; ++j) {
      int k = kbase + j;
      float w = (k < 64) ? Wih1[col*64 + k] : Whh1[col*128 + (k-64)];
      wh[WF0_H8*8 + t2*8 + j] = (_Float16)w;
    }
  } else if (tid < WF0_H8 + WF1_H8 + 768) {
    int t3 = tid - (WF0_H8 + WF1_H8);
    if (t3 < 256) { int col = (t3 & 3)*64 + (t3 >> 2);  bs[t3] = bih0[col] + bhh0[col]; }
    else { int p1 = t3 - 256; int col = (p1 & 3)*128 + (p1 >> 2); bs[t3] = bih1[col] + bhh1[col]; }
  }
}

// ---------------------------------------------------------------------------
// Main kernel: 1024 threads (16 waves), 16 rows/block, 1024 blocks.
// Wave w: layer0 coltile w (hidden 4w..4w+3), layer1 coltiles {2w,2w+1}
// (hidden 8w..8w+7). 2 barriers per timestep.
// ---------------------------------------------------------------------------
__global__ __launch_bounds__(1024, 4)
void lstm_kernel(const float* __restrict__ x, const _Float16* __restrict__ wh,
                 const float* __restrict__ bs,
                 const float* __restrict__ Wd1, const float* __restrict__ bd1,
                 const float* __restrict__ Wd2, const float* __restrict__ bd2,
                 float* __restrict__ out) {
  __shared__ _Float16 st0[2][R][S0];      // 6656 B  (double-buffered by t parity)
  __shared__ _Float16 st1[R][S1];         // 10496 B (h0 single, h1 double-buffered)
  __shared__ float    scr[16*512];        // 32768 B (per-wave 2x 1KB gather scratch)
  __shared__ float    hbuf[R][128];       // 8192 B  (fp32 h1 at t=T-1)
  __shared__ float    red[R][64];         // 4096 B  -> ~61 KB total

  const int tid  = threadIdx.x;
  const int w    = tid >> 6;
  const int lane = tid & 63;
  const int l15  = lane & 15;
  const int lg   = lane >> 4;            // 0..3
  const int a    = l15 >> 2;             // hidden sub-index in quad
  const int g    = l15 & 3;              // gate type: 0 i, 1 f, 2 g(tanh), 3 o
  const int r    = lg*4 + g;             // this lane's cell batch-row
  const int rowbase = blockIdx.x * R;

  // ---- weights -> registers (60 VGPR/wave), live across the whole T loop ----
  const half8* whv = (const half8*)wh;
  half8 wb0[3];
  #pragma unroll
  for (int kt = 0; kt < 3; ++kt) wb0[kt] = whv[(w*3 + kt)*64 + lane];
  half8 wb1[2][6];
  #pragma unroll
  for (int i = 0; i < 2; ++i)
    #pragma unroll
    for (int kt = 0; kt < 6; ++kt) wb1[i][kt] = whv[WF0_H8 + ((2*w+i)*6 + kt)*64 + lane];
  const float b0 = bs[w*16 + l15];
  float b1[2];
  #pragma unroll
  for (int i = 0; i < 2; ++i) b1[i] = bs[256 + (2*w+i)*16 + l15];

  // ---- per-lane nonlinearity constants: z = am*sigmoid(|sc|*v)+bm ----
  const float L2E = 1.4426950408889634f;
  const float sc = (g == 2) ? -2.0f*L2E : -L2E;
  const float am = (g == 2) ?  2.0f : 1.0f;
  const float bm = (g == 2) ? -1.0f : 0.0f;
  auto nl = [&](float v){ float y = frcp(1.0f + fexp2(sc*v)); return fmaf(am, y, bm); };
  auto tanh_f = [](float c){ return fmaf(2.0f, frcp(1.0f + fexp2(-2.8853900817779268f*c)), -1.0f); };

  // ---- register cell state ----
  float c0 = 0.0f, c1a = 0.0f, c1b = 0.0f;
  const int h0i = 4*w + a;               // layer0 hidden owned by this lane
  const int h1a = 8*w + a;               // layer1 hidden (ct=2w)
  const int h1b = 8*w + 4 + a;           // layer1 hidden (ct=2w+1)

  // ---- scratch pointers (t-invariant) ----
  float* sw  = scr + w*512;
  float* swr = sw + g*64 + a*16 + lg*4;  // write: [g][a][lg*4..+3]
  float* srd = sw + a*16 + r;            // read:  [g'][a][r] at srd[g'*64]

  // ---- zero-init LDS state ----
  for (int idx = tid; idx < 2*R*S0; idx += 1024) ((_Float16*)st0)[idx] = (_Float16)0.0f;
  for (int idx = tid; idx < R*S1;   idx += 1024) ((_Float16*)st1)[idx] = (_Float16)0.0f;
  __syncthreads();
  // x(t=0) -> st0[0]
  int xr = tid / 3, xq = tid % 3;
  if (tid < 48) {
    float4 v = *(const float4*)&x[((size_t)(rowbase + xr)*T_STEPS + 0)*F_IN + xq*4];
    half4 h4 = {(_Float16)v.x, (_Float16)v.y, (_Float16)v.z, (_Float16)v.w};
    *(half4*)&st0[0][xr][xq*4] = h4;
  }
  __syncthreads();

  for (int t = 0; t < T_STEPS; t += 2) {
    #pragma unroll
    for (int half = 0; half < 2; ++half) {
      const int tt = t + half;
      const int p  = half;               // tt & 1
      // ---------- Phase A: gates0 + cell0 ----------
      float4 xv = {0.0f, 0.0f, 0.0f, 0.0f};
      if (tid < 48) {                    // prefetch x(t+1); latency hides under MFMA
        int tn = (tt+1 < T_STEPS) ? tt+1 : tt;
        xv = *(const float4*)&x[((size_t)(rowbase + xr)*T_STEPS + tn)*F_IN + xq*4];
      }
      floatx4 acc = {b0, b0, b0, b0};
      #pragma unroll
      for (int kt = 0; kt < 3; ++kt) {
        half8 af = *(const half8*)&st0[p][l15][kt*32 + lg*8];
        acc = __builtin_amdgcn_mfma_f32_16x16x32_f16(af, wb0[kt], acc, 0, 0, 0);
      }
      floatx4 s;
      #pragma unroll
      for (int j = 0; j < 4; ++j) s[j] = nl(acc[j]);
      wavebar();
      *(floatx4*)swr = s;
      wavebar();
      float vi = srd[0], vf = srd[64], vg = srd[128], vo = srd[192];
      wavebar();
      c0 = fmaf(vf, c0, vi*vg);
      float h0v = vo * tanh_f(c0);
      _Float16 hh = (_Float16)h0v;
      st0[p^1][r][12 + h0i] = hh;        // feeds gates0(t+1)
      st1[r][h0i]           = hh;        // feeds gates1(t)
      if (tid < 48) {
        half4 h4 = {(_Float16)xv.x, (_Float16)xv.y, (_Float16)xv.z, (_Float16)xv.w};
        *(half4*)&st0[p^1][xr][xq*4] = h4;
      }
      __syncthreads();

      // ---------- Phase C: gates1 + cell1 ----------
      floatx4 acc0 = {b1[0], b1[0], b1[0], b1[0]};
      floatx4 acc1 = {b1[1], b1[1], b1[1], b1[1]};
      #pragma unroll
      for (int kt = 0; kt < 6; ++kt) {
        const int koff = (kt < 2) ? (kt*32 + lg*8)
                                  : (64 + p*128 + (kt-2)*32 + lg*8);
        half8 af = *(const half8*)&st1[l15][koff];
        acc0 = __builtin_amdgcn_mfma_f32_16x16x32_f16(af, wb1[0][kt], acc0, 0, 0, 0);
        acc1 = __builtin_amdgcn_mfma_f32_16x16x32_f16(af, wb1[1][kt], acc1, 0, 0, 0);
      }
      floatx4 s0, s1;
      #pragma unroll
      for (int j = 0; j < 4; ++j) { s0[j] = nl(acc0[j]); s1[j] = nl(acc1[j]); }
      wavebar();
      *(floatx4*)swr         = s0;
      *(floatx4*)(swr + 256) = s1;
      wavebar();
      float vi0 = srd[0],   vf0 = srd[64],     vg0 = srd[128],     vo0 = srd[192];
      float vi1 = srd[256], vf1 = srd[256+64], vg1 = srd[256+128], vo1 = srd[256+192];
      wavebar();
      c1a = fmaf(vf0, c1a, vi0*vg0);
      c1b = fmaf(vf1, c1b, vi1*vg1);
      float h1v0 = vo0 * tanh_f(c1a);
      float h1v1 = vo1 * tanh_f(c1b);
      st1[r][64 + (p^1)*128 + h1a] = (_Float16)h1v0;
      st1[r][64 + (p^1)*128 + h1b] = (_Float16)h1v1;
      if (tt == T_STEPS - 1) { hbuf[r][h1a] = h1v0; hbuf[r][h1b] = h1v1; }
      __syncthreads();
    }
  }

  // ---------- Head: out[r] = b_d2 + Wd2 @ (b_d1 + Wd1 @ h1[r]) ----------
  {
    int hr = tid & 15, jg = tid >> 4;    // 64 j-groups of 2
    float partial = 0.0f;
    #pragma unroll
    for (int jj = 0; jj < 2; ++jj) {
      int j = jg*2 + jj;
      float d = bd1[j];
      const float4* wrow = (const float4*)&Wd1[j*128];
      #pragma unroll 8
      for (int k4 = 0; k4 < 32; ++k4) {
        float4 wv = wrow[k4];
        const float4 hv = *(const float4*)&hbuf[hr][k4*4];
        d = fmaf(wv.x, hv.x, d); d = fmaf(wv.y, hv.y, d);
        d = fmaf(wv.z, hv.z, d); d = fmaf(wv.w, hv.w, d);
      }
      partial = fmaf(Wd2[j], d, partial);
    }
    red[hr][jg] = partial;
  }
  __syncthreads();
  if (tid < R) {
    float ssum = bd2[0];
    #pragma unroll
    for (int k = 0; k < 64; ++k) ssum += red[tid][k];
    out[rowbase + tid] = ssum;
  }
}

extern "C" void kernel_launch(void* const* d_in, const int* in_sizes, int n_in,
                              void* d_out, int out_size, void* d_ws, size_t ws_size,
                              hipStream_t stream) {
  const float* x    = (const float*)d_in[0];
  const float* Wih0 = (const float*)d_in[1];
  const float* Whh0 = (const float*)d_in[2];
  const float* bih0 = (const float*)d_in[3];
  const float* bhh0 = (const float*)d_in[4];
  const float* Wih1 = (const float*)d_in[5];
  const float* Whh1 = (const float*)d_in[6];
  const float* bih1 = (const float*)d_in[7];
  const float* bhh1 = (const float*)d_in[8];
  const float* Wd1  = (const float*)d_in[9];
  const float* bd1  = (const float*)d_in[10];
  const float* Wd2  = (const float*)d_in[11];
  const float* bd2  = (const float*)d_in[12];
  float* out = (float*)d_out;

  _Float16* wh  = (_Float16*)d_ws;
  float*    bsv = (float*)((char*)d_ws + (size_t)WH_TOTAL_HALVES * 2);

  prep_kernel<<<63, 256, 0, stream>>>(Wih0, Whh0, bih0, bhh0, Wih1, Whh1, bih1, bhh1, wh, bsv);
  lstm_kernel<<<1024, 1024, 0, stream>>>(x, wh, bsv, Wd1, bd1, Wd2, bd2, out);
}

// Round 4
// 998.045 us; speedup vs baseline: 1.2076x; 1.1065x over previous
//
#include <hip/hip_runtime.h>
#include <hip/hip_fp16.h>

// ============================================================================
// 2-layer LSTM (B=16384, T=128, F=12, H1=64, H2=128) + head, round 4.
// Changes vs R3:
//  - Weight fragments PINNED in VGPRs via empty inline-asm "+v" each t-iter
//    (R3's VGPR_Count=64 proved the compiler rematerialized the loads ->
//    ~32GB/dispatch L2 weight streaming, the 1100us plateau).
//  - LDS scratch gather replaced by DPP quad_perm 4x4 transpose (R3's 3.4e8
//    bank conflicts were the 8-way-conflict scratch ds_write_b128).
//  - scr[] LDS (32KB) and wavebars removed. 2 barriers/timestep unchanged.
// ============================================================================

#define T_STEPS 128
#define F_IN    12
#define R       16      // batch rows per block
#define S0      104     // st0 row stride (halves): [x12|h0 64|zero20|pad8], 208B=13*16B
#define S1      328     // st1 row stride (halves): [h0 64|h1_p0 128|h1_p1 128|pad8], 656B=41*16B

#define WF0_H8  (16*3*64)
#define WF1_H8  (32*6*64)
#define WH_TOTAL_HALVES ((WF0_H8 + WF1_H8)*8)   // 245760 B

typedef _Float16 half8 __attribute__((ext_vector_type(8)));
typedef _Float16 half4 __attribute__((ext_vector_type(4)));
typedef float   floatx4 __attribute__((ext_vector_type(4)));
typedef int     intx4  __attribute__((ext_vector_type(4)));

__device__ __forceinline__ float fexp2(float x){
#if __has_builtin(__builtin_amdgcn_exp2f)
  return __builtin_amdgcn_exp2f(x);
#else
  return exp2f(x);
#endif
}
__device__ __forceinline__ float frcp(float x){
#if __has_builtin(__builtin_amdgcn_rcpf)
  return __builtin_amdgcn_rcpf(x);
#else
  return 1.0f / x;
#endif
}

// DPP quad_perm helpers: permute within each aligned group of 4 lanes.
__device__ __forceinline__ float qpx1(float v){   // lane q reads q^1
  return __int_as_float(__builtin_amdgcn_update_dpp(
      0, __float_as_int(v), 0xB1 /*[1,0,3,2]*/, 0xF, 0xF, true));
}
__device__ __forceinline__ float qpx2(float v){   // lane q reads q^2
  return __int_as_float(__builtin_amdgcn_update_dpp(
      0, __float_as_int(v), 0x4E /*[2,3,0,1]*/, 0xF, 0xF, true));
}
// In-register 4x4 transpose across a lane quad: input s[j] = V(q, j) for this
// lane's quad index q; output d[j] = V(j, q).  8 DPP + 8 cndmask.
__device__ __forceinline__ floatx4 qtrans4(floatx4 s, int g){
  float e0 = qpx1(s[1]), e1 = qpx1(s[0]), e2 = qpx1(s[3]), e3 = qpx1(s[2]);
  const bool lo = (g & 1);
  float m0 = lo ? e0   : s[0];
  float m1 = lo ? s[1] : e1;
  float m2 = lo ? e2   : s[2];
  float m3 = lo ? s[3] : e3;
  float f0 = qpx2(m2), f1 = qpx2(m3), f2 = qpx2(m0), f3 = qpx2(m1);
  const bool hi = (g & 2);
  floatx4 d;
  d[0] = hi ? f0 : m0;
  d[1] = hi ? f1 : m1;
  d[2] = hi ? m2 : f2;
  d[3] = hi ? m3 : f3;
  return d;
}

// ---------------------------------------------------------------------------
// Prep: pack fp16 MFMA B-fragments (PERMUTED columns p=4h+g) + fused biases.
// ---------------------------------------------------------------------------
__global__ void prep_kernel(const float* __restrict__ Wih0, const float* __restrict__ Whh0,
                            const float* __restrict__ bih0, const float* __restrict__ bhh0,
                            const float* __restrict__ Wih1, const float* __restrict__ Whh1,
                            const float* __restrict__ bih1, const float* __restrict__ bhh1,
                            _Float16* __restrict__ wh, float* __restrict__ bs) {
  int tid = blockIdx.x * 256 + threadIdx.x;
  if (tid < WF0_H8) {
    int lane = tid & 63; int kt = (tid >> 6) % 3; int ct = tid / (64*3);
    int p = ct*16 + (lane & 15);
    int col = (p & 3)*64 + (p >> 2);          // orig row of W0cat: gate*64 + hidden
    int kbase = kt*32 + (lane >> 4)*8;
    #pragma unroll
    for (int j = 0; j < 8; ++j) {
      int k = kbase + j; float w = 0.0f;
      if (k < 12) w = Wih0[col*12 + k];
      else if (k < 76) w = Whh0[col*64 + (k-12)];
      wh[tid*8 + j] = (_Float16)w;
    }
  } else if (tid < WF0_H8 + WF1_H8) {
    int t2 = tid - WF0_H8;
    int lane = t2 & 63; int kt = (t2 >> 6) % 6; int ct = t2 / (64*6);
    int p = ct*16 + (lane & 15);
    int col = (p & 3)*128 + (p >> 2);         // gate*128 + hidden
    int kbase = kt*32 + (lane >> 4)*8;
    #pragma unroll
    for (int j = 0; j < 8; ++j) {
      int k = kbase + j;
      float w = (k < 64) ? Wih1[col*64 + k] : Whh1[col*128 + (k-64)];
      wh[WF0_H8*8 + t2*8 + j] = (_Float16)w;
    }
  } else if (tid < WF0_H8 + WF1_H8 + 768) {
    int t3 = tid - (WF0_H8 + WF1_H8);
    if (t3 < 256) { int col = (t3 & 3)*64 + (t3 >> 2);  bs[t3] = bih0[col] + bhh0[col]; }
    else { int p1 = t3 - 256; int col = (p1 & 3)*128 + (p1 >> 2); bs[t3] = bih1[col] + bhh1[col]; }
  }
}

// ---------------------------------------------------------------------------
// Main kernel: 1024 threads (16 waves), 16 rows/block, 1024 blocks.
// Wave w: layer0 coltile w (hidden 4w..4w+3), layer1 coltiles {2w,2w+1}.
// ---------------------------------------------------------------------------
__global__ __launch_bounds__(1024, 4)
void lstm_kernel(const float* __restrict__ x, const _Float16* __restrict__ wh,
                 const float* __restrict__ bs,
                 const float* __restrict__ Wd1, const float* __restrict__ bd1,
                 const float* __restrict__ Wd2, const float* __restrict__ bd2,
                 float* __restrict__ out) {
  __shared__ _Float16 st0[2][R][S0];      // 6656 B  (double-buffered by t parity)
  __shared__ _Float16 st1[R][S1];         // 10496 B (h0 single, h1 double-buffered)
  __shared__ float    hbuf[R][128];       // 8192 B  (fp32 h1 at t=T-1)
  __shared__ float    red[R][64];         // 4096 B  -> ~29 KB total

  const int tid  = threadIdx.x;
  const int w    = tid >> 6;
  const int lane = tid & 63;
  const int l15  = lane & 15;
  const int lg   = lane >> 4;            // 0..3
  const int a    = l15 >> 2;             // hidden sub-index in quad
  const int g    = l15 & 3;              // gate type / quad index
  const int r    = lg*4 + g;             // this lane's cell batch-row
  const int rowbase = blockIdx.x * R;

  // ---- weights -> registers, PINNED across the T loop ----
  const intx4* whi = (const intx4*)wh;
  intx4 wb0i[3];
  #pragma unroll
  for (int kt = 0; kt < 3; ++kt) wb0i[kt] = whi[(w*3 + kt)*64 + lane];
  intx4 wb1i[2][6];
  #pragma unroll
  for (int i = 0; i < 2; ++i)
    #pragma unroll
    for (int kt = 0; kt < 6; ++kt) wb1i[i][kt] = whi[WF0_H8 + ((2*w+i)*6 + kt)*64 + lane];
  float b0 = bs[w*16 + l15];
  float b1[2];
  #pragma unroll
  for (int i = 0; i < 2; ++i) b1[i] = bs[256 + (2*w+i)*16 + l15];

  // ---- per-lane nonlinearity: z = am*sigmoid(|sc|*v)+bm (tanh for g==2) ----
  const float L2E = 1.4426950408889634f;
  const float sc = (g == 2) ? -2.0f*L2E : -L2E;
  const float am = (g == 2) ?  2.0f : 1.0f;
  const float bm = (g == 2) ? -1.0f : 0.0f;
  auto nl = [&](float v){ float y = frcp(1.0f + fexp2(sc*v)); return fmaf(am, y, bm); };
  auto tanh_f = [](float c){ return fmaf(2.0f, frcp(1.0f + fexp2(-2.8853900817779268f*c)), -1.0f); };

  // ---- register cell state ----
  float c0 = 0.0f, c1a = 0.0f, c1b = 0.0f;
  const int h0i = 4*w + a;
  const int h1a = 8*w + a;
  const int h1b = 8*w + 4 + a;

  // ---- zero-init LDS state ----
  for (int idx = tid; idx < 2*R*S0; idx += 1024) ((_Float16*)st0)[idx] = (_Float16)0.0f;
  for (int idx = tid; idx < R*S1;   idx += 1024) ((_Float16*)st1)[idx] = (_Float16)0.0f;
  __syncthreads();
  int xr = tid / 3, xq = tid % 3;
  if (tid < 48) {
    float4 v = *(const float4*)&x[((size_t)(rowbase + xr)*T_STEPS + 0)*F_IN + xq*4];
    half4 h4 = {(_Float16)v.x, (_Float16)v.y, (_Float16)v.z, (_Float16)v.w};
    *(half4*)&st0[0][xr][xq*4] = h4;
  }
  __syncthreads();

  for (int t = 0; t < T_STEPS; t += 2) {
    // Pin: compiler must treat these as live, register-resident values --
    // forbids rematerializing the global loads inside the loop.
    #pragma unroll
    for (int kt = 0; kt < 3; ++kt) asm volatile("" : "+v"(wb0i[kt]));
    #pragma unroll
    for (int i = 0; i < 2; ++i)
      #pragma unroll
      for (int kt = 0; kt < 6; ++kt) asm volatile("" : "+v"(wb1i[i][kt]));
    asm volatile("" : "+v"(b0), "+v"(b1[0]), "+v"(b1[1]));

    #pragma unroll
    for (int half = 0; half < 2; ++half) {
      const int tt = t + half;
      const int p  = half;
      // ---------- Phase A: gates0 + cell0 ----------
      float4 xv = {0.0f, 0.0f, 0.0f, 0.0f};
      if (tid < 48) {                    // prefetch x(t+1); hides under MFMA
        int tn = (tt+1 < T_STEPS) ? tt+1 : tt;
        xv = *(const float4*)&x[((size_t)(rowbase + xr)*T_STEPS + tn)*F_IN + xq*4];
      }
      floatx4 acc = {b0, b0, b0, b0};
      #pragma unroll
      for (int kt = 0; kt < 3; ++kt) {
        half8 af = *(const half8*)&st0[p][l15][kt*32 + lg*8];
        acc = __builtin_amdgcn_mfma_f32_16x16x32_f16(af, __builtin_bit_cast(half8, wb0i[kt]), acc, 0, 0, 0);
      }
      floatx4 s;
      #pragma unroll
      for (int j = 0; j < 4; ++j) s[j] = nl(acc[j]);
      floatx4 d = qtrans4(s, g);         // d = (i,f,g~,o) for row r, hidden h0i
      c0 = fmaf(d[1], c0, d[0]*d[2]);
      float h0v = d[3] * tanh_f(c0);
      _Float16 hh = (_Float16)h0v;
      st0[p^1][r][12 + h0i] = hh;        // feeds gates0(t+1)
      st1[r][h0i]           = hh;        // feeds gates1(t)
      if (tid < 48) {
        half4 h4 = {(_Float16)xv.x, (_Float16)xv.y, (_Float16)xv.z, (_Float16)xv.w};
        *(half4*)&st0[p^1][xr][xq*4] = h4;
      }
      __syncthreads();

      // ---------- Phase C: gates1 + cell1 ----------
      floatx4 acc0 = {b1[0], b1[0], b1[0], b1[0]};
      floatx4 acc1 = {b1[1], b1[1], b1[1], b1[1]};
      #pragma unroll
      for (int kt = 0; kt < 6; ++kt) {
        const int koff = (kt < 2) ? (kt*32 + lg*8)
                                  : (64 + p*128 + (kt-2)*32 + lg*8);
        half8 af = *(const half8*)&st1[l15][koff];
        acc0 = __builtin_amdgcn_mfma_f32_16x16x32_f16(af, __builtin_bit_cast(half8, wb1i[0][kt]), acc0, 0, 0, 0);
        acc1 = __builtin_amdgcn_mfma_f32_16x16x32_f16(af, __builtin_bit_cast(half8, wb1i[1][kt]), acc1, 0, 0, 0);
      }
      floatx4 s0, s1;
      #pragma unroll
      for (int j = 0; j < 4; ++j) { s0[j] = nl(acc0[j]); s1[j] = nl(acc1[j]); }
      floatx4 da = qtrans4(s0, g);
      floatx4 db = qtrans4(s1, g);
      c1a = fmaf(da[1], c1a, da[0]*da[2]);
      c1b = fmaf(db[1], c1b, db[0]*db[2]);
      float h1v0 = da[3] * tanh_f(c1a);
      float h1v1 = db[3] * tanh_f(c1b);
      st1[r][64 + (p^1)*128 + h1a] = (_Float16)h1v0;
      st1[r][64 + (p^1)*128 + h1b] = (_Float16)h1v1;
      if (tt == T_STEPS - 1) { hbuf[r][h1a] = h1v0; hbuf[r][h1b] = h1v1; }
      __syncthreads();
    }
  }

  // ---------- Head: out[r] = b_d2 + Wd2 @ (b_d1 + Wd1 @ h1[r]) ----------
  {
    int hr = tid & 15, jg = tid >> 4;    // 64 j-groups of 2
    float partial = 0.0f;
    #pragma unroll
    for (int jj = 0; jj < 2; ++jj) {
      int j = jg*2 + jj;
      float dacc = bd1[j];
      const float4* wrow = (const float4*)&Wd1[j*128];
      #pragma unroll 8
      for (int k4 = 0; k4 < 32; ++k4) {
        float4 wv = wrow[k4];
        const float4 hv = *(const float4*)&hbuf[hr][k4*4];
        dacc = fmaf(wv.x, hv.x, dacc); dacc = fmaf(wv.y, hv.y, dacc);
        dacc = fmaf(wv.z, hv.z, dacc); dacc = fmaf(wv.w, hv.w, dacc);
      }
      partial = fmaf(Wd2[j], dacc, partial);
    }
    red[hr][jg] = partial;
  }
  __syncthreads();
  if (tid < R) {
    float ssum = bd2[0];
    #pragma unroll
    for (int k = 0; k < 64; ++k) ssum += red[tid][k];
    out[rowbase + tid] = ssum;
  }
}

extern "C" void kernel_launch(void* const* d_in, const int* in_sizes, int n_in,
                              void* d_out, int out_size, void* d_ws, size_t ws_size,
                              hipStream_t stream) {
  const float* x    = (const float*)d_in[0];
  const float* Wih0 = (const float*)d_in[1];
  const float* Whh0 = (const float*)d_in[2];
  const float* bih0 = (const float*)d_in[3];
  const float* bhh0 = (const float*)d_in[4];
  const float* Wih1 = (const float*)d_in[5];
  const float* Whh1 = (const float*)d_in[6];
  const float* bih1 = (const float*)d_in[7];
  const float* bhh1 = (const float*)d_in[8];
  const float* Wd1  = (const float*)d_in[9];
  const float* bd1  = (const float*)d_in[10];
  const float* Wd2  = (const float*)d_in[11];
  const float* bd2  = (const float*)d_in[12];
  float* out = (float*)d_out;

  _Float16* wh  = (_Float16*)d_ws;
  float*    bsv = (float*)((char*)d_ws + (size_t)WH_TOTAL_HALVES * 2);

  prep_kernel<<<63, 256, 0, stream>>>(Wih0, Whh0, bih0, bhh0, Wih1, Whh1, bih1, bhh1, wh, bsv);
  lstm_kernel<<<1024, 1024, 0, stream>>>(x, wh, bsv, Wd1, bd1, Wd2, bd2, out);
}

// Round 5
// 981.615 us; speedup vs baseline: 1.2278x; 1.0167x over previous
//
#include <hip/hip_runtime.h>
#include <hip/hip_fp16.h>

// ============================================================================
// 2-layer LSTM (B=16384, T=128, F=12, H1=64, H2=128) + head, round 5.
// Changes vs R4:
//  - __launch_bounds__(1024, 1): R4's (1024,4) was interpreted as min-4-
//    BLOCKS/CU (CUDA semantics) -> VGPR cap ~32 -> forced spill/fill of the
//    60 pinned weight VGPRs every iter (~30GB scratch traffic = the 1000us).
//    (1024,1) gives a 128-VGPR cap under either semantics.
//  - Transcendentals as raw asm v_exp_f32/v_rcp_f32 (no -ffast-math: 1/x was
//    lowering to ~10-op IEEE div; library exp2f adds fixup code).
//  - Nonlinearity applied AFTER the DPP transpose: gate type is a register-
//    slot constant, not a per-lane cndmask'd coefficient set.
// ============================================================================

#define T_STEPS 128
#define F_IN    12
#define R       16      // batch rows per block
#define S0      104     // st0 row stride (halves): [x12|h0 64|zero20|pad8], 208B=13*16B
#define S1      328     // st1 row stride (halves): [h0 64|h1_p0 128|h1_p1 128|pad8], 656B=41*16B

#define WF0_H8  (16*3*64)
#define WF1_H8  (32*6*64)
#define WH_TOTAL_HALVES ((WF0_H8 + WF1_H8)*8)   // 245760 B

typedef _Float16 half8 __attribute__((ext_vector_type(8)));
typedef _Float16 half4 __attribute__((ext_vector_type(4)));
typedef float   floatx4 __attribute__((ext_vector_type(4)));
typedef int     intx4  __attribute__((ext_vector_type(4)));

// Single-instruction transcendentals (gfx9-family is hw-interlocked; the
// compiler's scheduler treats asm conservatively).
__device__ __forceinline__ float vexp2(float x){
  float r; asm("v_exp_f32 %0, %1" : "=v"(r) : "v"(x)); return r;
}
__device__ __forceinline__ float vrcp(float x){
  float r; asm("v_rcp_f32 %0, %1" : "=v"(r) : "v"(x)); return r;
}
__device__ __forceinline__ float sigf(float x){        // sigmoid
  return vrcp(1.0f + vexp2(-1.4426950408889634f * x));
}
__device__ __forceinline__ float tanhf_(float x){      // tanh
  return fmaf(2.0f, vrcp(1.0f + vexp2(-2.8853900817779268f * x)), -1.0f);
}

// DPP quad_perm helpers: permute within each aligned group of 4 lanes.
__device__ __forceinline__ float qpx1(float v){   // lane q reads q^1
  return __int_as_float(__builtin_amdgcn_update_dpp(
      0, __float_as_int(v), 0xB1 /*[1,0,3,2]*/, 0xF, 0xF, true));
}
__device__ __forceinline__ float qpx2(float v){   // lane q reads q^2
  return __int_as_float(__builtin_amdgcn_update_dpp(
      0, __float_as_int(v), 0x4E /*[2,3,0,1]*/, 0xF, 0xF, true));
}
// In-register 4x4 transpose across a lane quad: input s[j] = V(q, j) for this
// lane's quad index q; output d[j] = V(j, q).  8 DPP + 8 cndmask.
__device__ __forceinline__ floatx4 qtrans4(floatx4 s, int g){
  float e0 = qpx1(s[1]), e1 = qpx1(s[0]), e2 = qpx1(s[3]), e3 = qpx1(s[2]);
  const bool lo = (g & 1);
  float m0 = lo ? e0   : s[0];
  float m1 = lo ? s[1] : e1;
  float m2 = lo ? e2   : s[2];
  float m3 = lo ? s[3] : e3;
  float f0 = qpx2(m2), f1 = qpx2(m3), f2 = qpx2(m0), f3 = qpx2(m1);
  const bool hi = (g & 2);
  floatx4 d;
  d[0] = hi ? f0 : m0;
  d[1] = hi ? f1 : m1;
  d[2] = hi ? m2 : f2;
  d[3] = hi ? m3 : f3;
  return d;
}

// ---------------------------------------------------------------------------
// Prep: pack fp16 MFMA B-fragments (PERMUTED columns p=4h+g) + fused biases.
// ---------------------------------------------------------------------------
__global__ void prep_kernel(const float* __restrict__ Wih0, const float* __restrict__ Whh0,
                            const float* __restrict__ bih0, const float* __restrict__ bhh0,
                            const float* __restrict__ Wih1, const float* __restrict__ Whh1,
                            const float* __restrict__ bih1, const float* __restrict__ bhh1,
                            _Float16* __restrict__ wh, float* __restrict__ bs) {
  int tid = blockIdx.x * 256 + threadIdx.x;
  if (tid < WF0_H8) {
    int lane = tid & 63; int kt = (tid >> 6) % 3; int ct = tid / (64*3);
    int p = ct*16 + (lane & 15);
    int col = (p & 3)*64 + (p >> 2);          // orig row of W0cat: gate*64 + hidden
    int kbase = kt*32 + (lane >> 4)*8;
    #pragma unroll
    for (int j = 0; j < 8; ++j) {
      int k = kbase + j; float w = 0.0f;
      if (k < 12) w = Wih0[col*12 + k];
      else if (k < 76) w = Whh0[col*64 + (k-12)];
      wh[tid*8 + j] = (_Float16)w;
    }
  } else if (tid < WF0_H8 + WF1_H8) {
    int t2 = tid - WF0_H8;
    int lane = t2 & 63; int kt = (t2 >> 6) % 6; int ct = t2 / (64*6);
    int p = ct*16 + (lane & 15);
    int col = (p & 3)*128 + (p >> 2);         // gate*128 + hidden
    int kbase = kt*32 + (lane >> 4)*8;
    #pragma unroll
    for (int j = 0; j < 8; ++j) {
      int k = kbase + j;
      float w = (k < 64) ? Wih1[col*64 + k] : Whh1[col*128 + (k-64)];
      wh[WF0_H8*8 + t2*8 + j] = (_Float16)w;
    }
  } else if (tid < WF0_H8 + WF1_H8 + 768) {
    int t3 = tid - (WF0_H8 + WF1_H8);
    if (t3 < 256) { int col = (t3 & 3)*64 + (t3 >> 2);  bs[t3] = bih0[col] + bhh0[col]; }
    else { int p1 = t3 - 256; int col = (p1 & 3)*128 + (p1 >> 2); bs[t3] = bih1[col] + bhh1[col]; }
  }
}

// ---------------------------------------------------------------------------
// Main kernel: 1024 threads (16 waves), 16 rows/block, 1024 blocks.
// Wave w: layer0 coltile w (hidden 4w..4w+3), layer1 coltiles {2w,2w+1}.
// ---------------------------------------------------------------------------
__global__ __launch_bounds__(1024, 1)
void lstm_kernel(const float* __restrict__ x, const _Float16* __restrict__ wh,
                 const float* __restrict__ bs,
                 const float* __restrict__ Wd1, const float* __restrict__ bd1,
                 const float* __restrict__ Wd2, const float* __restrict__ bd2,
                 float* __restrict__ out) {
  __shared__ _Float16 st0[2][R][S0];      // 6656 B  (double-buffered by t parity)
  __shared__ _Float16 st1[R][S1];         // 10496 B (h0 single, h1 double-buffered)
  __shared__ float    hbuf[R][128];       // 8192 B  (fp32 h1 at t=T-1)
  __shared__ float    red[R][64];         // 4096 B  -> ~29 KB total

  const int tid  = threadIdx.x;
  const int w    = tid >> 6;
  const int lane = tid & 63;
  const int l15  = lane & 15;
  const int lg   = lane >> 4;            // 0..3
  const int a    = l15 >> 2;             // hidden sub-index in quad
  const int g    = l15 & 3;              // quad index
  const int r    = lg*4 + g;             // this lane's cell batch-row
  const int rowbase = blockIdx.x * R;

  // ---- weights -> registers, PINNED across the T loop ----
  const intx4* whi = (const intx4*)wh;
  intx4 wb0i[3];
  #pragma unroll
  for (int kt = 0; kt < 3; ++kt) wb0i[kt] = whi[(w*3 + kt)*64 + lane];
  intx4 wb1i[2][6];
  #pragma unroll
  for (int i = 0; i < 2; ++i)
    #pragma unroll
    for (int kt = 0; kt < 6; ++kt) wb1i[i][kt] = whi[WF0_H8 + ((2*w+i)*6 + kt)*64 + lane];
  float b0 = bs[w*16 + l15];
  float b1[2];
  #pragma unroll
  for (int i = 0; i < 2; ++i) b1[i] = bs[256 + (2*w+i)*16 + l15];

  // ---- register cell state ----
  float c0 = 0.0f, c1a = 0.0f, c1b = 0.0f;
  const int h0i = 4*w + a;
  const int h1a = 8*w + a;
  const int h1b = 8*w + 4 + a;

  // ---- zero-init LDS state ----
  for (int idx = tid; idx < 2*R*S0; idx += 1024) ((_Float16*)st0)[idx] = (_Float16)0.0f;
  for (int idx = tid; idx < R*S1;   idx += 1024) ((_Float16*)st1)[idx] = (_Float16)0.0f;
  __syncthreads();
  int xr = tid / 3, xq = tid % 3;
  if (tid < 48) {
    float4 v = *(const float4*)&x[((size_t)(rowbase + xr)*T_STEPS + 0)*F_IN + xq*4];
    half4 h4 = {(_Float16)v.x, (_Float16)v.y, (_Float16)v.z, (_Float16)v.w};
    *(half4*)&st0[0][xr][xq*4] = h4;
  }
  __syncthreads();

  for (int t = 0; t < T_STEPS; t += 2) {
    // Pin: values must flow through VGPRs each iteration -> no remat of the
    // global loads; with the 128-VGPR cap they stay resident (no spill).
    #pragma unroll
    for (int kt = 0; kt < 3; ++kt) asm volatile("" : "+v"(wb0i[kt]));
    #pragma unroll
    for (int i = 0; i < 2; ++i)
      #pragma unroll
      for (int kt = 0; kt < 6; ++kt) asm volatile("" : "+v"(wb1i[i][kt]));
    asm volatile("" : "+v"(b0), "+v"(b1[0]), "+v"(b1[1]));

    #pragma unroll
    for (int half = 0; half < 2; ++half) {
      const int tt = t + half;
      const int p  = half;
      // ---------- Phase A: gates0 + cell0 ----------
      float4 xv = {0.0f, 0.0f, 0.0f, 0.0f};
      if (tid < 48) {                    // prefetch x(t+1); hides under MFMA
        int tn = (tt+1 < T_STEPS) ? tt+1 : tt;
        xv = *(const float4*)&x[((size_t)(rowbase + xr)*T_STEPS + tn)*F_IN + xq*4];
      }
      floatx4 acc = {b0, b0, b0, b0};
      #pragma unroll
      for (int kt = 0; kt < 3; ++kt) {
        half8 af = *(const half8*)&st0[p][l15][kt*32 + lg*8];
        acc = __builtin_amdgcn_mfma_f32_16x16x32_f16(af, __builtin_bit_cast(half8, wb0i[kt]), acc, 0, 0, 0);
      }
      // transpose raw pre-activations, then slot-constant nonlinearities:
      // d = (i_pre, f_pre, g_pre, o_pre) for batch-row r, hidden h0i
      floatx4 d = qtrans4(acc, g);
      c0 = fmaf(sigf(d[1]), c0, sigf(d[0]) * tanhf_(d[2]));
      float h0v = sigf(d[3]) * tanhf_(c0);
      _Float16 hh = (_Float16)h0v;
      st0[p^1][r][12 + h0i] = hh;        // feeds gates0(t+1)
      st1[r][h0i]           = hh;        // feeds gates1(t)
      if (tid < 48) {
        half4 h4 = {(_Float16)xv.x, (_Float16)xv.y, (_Float16)xv.z, (_Float16)xv.w};
        *(half4*)&st0[p^1][xr][xq*4] = h4;
      }
      __syncthreads();

      // ---------- Phase C: gates1 + cell1 ----------
      floatx4 acc0 = {b1[0], b1[0], b1[0], b1[0]};
      floatx4 acc1 = {b1[1], b1[1], b1[1], b1[1]};
      #pragma unroll
      for (int kt = 0; kt < 6; ++kt) {
        const int koff = (kt < 2) ? (kt*32 + lg*8)
                                  : (64 + p*128 + (kt-2)*32 + lg*8);
        half8 af = *(const half8*)&st1[l15][koff];
        acc0 = __builtin_amdgcn_mfma_f32_16x16x32_f16(af, __builtin_bit_cast(half8, wb1i[0][kt]), acc0, 0, 0, 0);
        acc1 = __builtin_amdgcn_mfma_f32_16x16x32_f16(af, __builtin_bit_cast(half8, wb1i[1][kt]), acc1, 0, 0, 0);
      }
      floatx4 da = qtrans4(acc0, g);
      floatx4 db = qtrans4(acc1, g);
      c1a = fmaf(sigf(da[1]), c1a, sigf(da[0]) * tanhf_(da[2]));
      c1b = fmaf(sigf(db[1]), c1b, sigf(db[0]) * tanhf_(db[2]));
      float h1v0 = sigf(da[3]) * tanhf_(c1a);
      float h1v1 = sigf(db[3]) * tanhf_(c1b);
      st1[r][64 + (p^1)*128 + h1a] = (_Float16)h1v0;
      st1[r][64 + (p^1)*128 + h1b] = (_Float16)h1v1;
      if (tt == T_STEPS - 1) { hbuf[r][h1a] = h1v0; hbuf[r][h1b] = h1v1; }
      __syncthreads();
    }
  }

  // ---------- Head: out[r] = b_d2 + Wd2 @ (b_d1 + Wd1 @ h1[r]) ----------
  {
    int hr = tid & 15, jg = tid >> 4;    // 64 j-groups of 2
    float partial = 0.0f;
    #pragma unroll
    for (int jj = 0; jj < 2; ++jj) {
      int j = jg*2 + jj;
      float dacc = bd1[j];
      const float4* wrow = (const float4*)&Wd1[j*128];
      #pragma unroll 8
      for (int k4 = 0; k4 < 32; ++k4) {
        float4 wv = wrow[k4];
        const float4 hv = *(const float4*)&hbuf[hr][k4*4];
        dacc = fmaf(wv.x, hv.x, dacc); dacc = fmaf(wv.y, hv.y, dacc);
        dacc = fmaf(wv.z, hv.z, dacc); dacc = fmaf(wv.w, hv.w, dacc);
      }
      partial = fmaf(Wd2[j], dacc, partial);
    }
    red[hr][jg] = partial;
  }
  __syncthreads();
  if (tid < R) {
    float ssum = bd2[0];
    #pragma unroll
    for (int k = 0; k < 64; ++k) ssum += red[tid][k];
    out[rowbase + tid] = ssum;
  }
}

extern "C" void kernel_launch(void* const* d_in, const int* in_sizes, int n_in,
                              void* d_out, int out_size, void* d_ws, size_t ws_size,
                              hipStream_t stream) {
  const float* x    = (const float*)d_in[0];
  const float* Wih0 = (const float*)d_in[1];
  const float* Whh0 = (const float*)d_in[2];
  const float* bih0 = (const float*)d_in[3];
  const float* bhh0 = (const float*)d_in[4];
  const float* Wih1 = (const float*)d_in[5];
  const float* Whh1 = (const float*)d_in[6];
  const float* bih1 = (const float*)d_in[7];
  const float* bhh1 = (const float*)d_in[8];
  const float* Wd1  = (const float*)d_in[9];
  const float* bd1  = (const float*)d_in[10];
  const float* Wd2  = (const float*)d_in[11];
  const float* bd2  = (const float*)d_in[12];
  float* out = (float*)d_out;

  _Float16* wh  = (_Float16*)d_ws;
  float*    bsv = (float*)((char*)d_ws + (size_t)WH_TOTAL_HALVES * 2);

  prep_kernel<<<63, 256, 0, stream>>>(Wih0, Whh0, bih0, bhh0, Wih1, Whh1, bih1, bhh1, wh, bsv);
  lstm_kernel<<<1024, 1024, 0, stream>>>(x, wh, bsv, Wd1, bd1, Wd2, bd2, out);
}

// Round 6
// 881.234 us; speedup vs baseline: 1.3677x; 1.1139x over previous
//
#include <hip/hip_runtime.h>
#include <hip/hip_fp16.h>

// ============================================================================
// 2-layer LSTM (B=16384, T=128, F=12, H1=64, H2=128) + head, round 6.
// Changes vs R5 (981us, VALUBusy 60, MfmaUtil 20, conflicts 1.4e8):
//  - SOFTWARE-PIPELINED LAYERS: phase P(t) = { C(t) || A(t+1) } with ONE
//    barrier per timestep (A(t+1) needs only h0(t), not C(t)). 15 MFMA +
//    2-layer cell updates per phase -> 2x ILP, half the barriers.
//  - XOR-SWIZZLED LDS: st0/st1 rows are power-of-2 stride (128/512 halves);
//    physical 8-half block = logical_block ^ (row&7). Keeps 16B-aligned
//    b128 frag reads conflict-free AND spreads the b16 h0/h1 scatter writes
//    over 8 banks (R5's 1.4e8 conflicts were these writes at 4-dword-aligned
//    row strides: 16 rows -> 1 bank group).
//  - hbuf stride 132, red stride 65 (head-tail bank fixes).
// Weights live in AGPRs (R5 post-mortem: WRITE_SIZE~0 proved no spill; the
// unified-file AGPR parking IS residency since MFMA reads B from AGPR).
// ============================================================================

#define T_STEPS 128
#define F_IN    12
#define R       16      // batch rows per block

#define WF0_H8  (16*3*64)
#define WF1_H8  (32*6*64)
#define WH_TOTAL_HALVES ((WF0_H8 + WF1_H8)*8)   // 245760 B

typedef _Float16 half8 __attribute__((ext_vector_type(8)));
typedef _Float16 half4 __attribute__((ext_vector_type(4)));
typedef float   floatx4 __attribute__((ext_vector_type(4)));
typedef int     intx4  __attribute__((ext_vector_type(4)));

__device__ __forceinline__ float vexp2(float x){
  float r; asm("v_exp_f32 %0, %1" : "=v"(r) : "v"(x)); return r;
}
__device__ __forceinline__ float vrcp(float x){
  float r; asm("v_rcp_f32 %0, %1" : "=v"(r) : "v"(x)); return r;
}
__device__ __forceinline__ float sigf(float x){        // sigmoid
  return vrcp(1.0f + vexp2(-1.4426950408889634f * x));
}
__device__ __forceinline__ float tanhf_(float x){      // tanh
  return fmaf(2.0f, vrcp(1.0f + vexp2(-2.8853900817779268f * x)), -1.0f);
}

// DPP quad_perm helpers.
__device__ __forceinline__ float qpx1(float v){
  return __int_as_float(__builtin_amdgcn_update_dpp(
      0, __float_as_int(v), 0xB1 /*[1,0,3,2]*/, 0xF, 0xF, true));
}
__device__ __forceinline__ float qpx2(float v){
  return __int_as_float(__builtin_amdgcn_update_dpp(
      0, __float_as_int(v), 0x4E /*[2,3,0,1]*/, 0xF, 0xF, true));
}
// 4x4 transpose across a lane quad (verified R4/R5).
__device__ __forceinline__ floatx4 qtrans4(floatx4 s, int g){
  float e0 = qpx1(s[1]), e1 = qpx1(s[0]), e2 = qpx1(s[3]), e3 = qpx1(s[2]);
  const bool lo = (g & 1);
  float m0 = lo ? e0   : s[0];
  float m1 = lo ? s[1] : e1;
  float m2 = lo ? e2   : s[2];
  float m3 = lo ? s[3] : e3;
  float f0 = qpx2(m2), f1 = qpx2(m3), f2 = qpx2(m0), f3 = qpx2(m1);
  const bool hi = (g & 2);
  floatx4 d;
  d[0] = hi ? f0 : m0;
  d[1] = hi ? f1 : m1;
  d[2] = hi ? m2 : f2;
  d[3] = hi ? m3 : f3;
  return d;
}

// ---------------------------------------------------------------------------
// Prep: pack fp16 MFMA B-fragments (PERMUTED columns p=4h+g) + fused biases.
// ---------------------------------------------------------------------------
__global__ void prep_kernel(const float* __restrict__ Wih0, const float* __restrict__ Whh0,
                            const float* __restrict__ bih0, const float* __restrict__ bhh0,
                            const float* __restrict__ Wih1, const float* __restrict__ Whh1,
                            const float* __restrict__ bih1, const float* __restrict__ bhh1,
                            _Float16* __restrict__ wh, float* __restrict__ bs) {
  int tid = blockIdx.x * 256 + threadIdx.x;
  if (tid < WF0_H8) {
    int lane = tid & 63; int kt = (tid >> 6) % 3; int ct = tid / (64*3);
    int p = ct*16 + (lane & 15);
    int col = (p & 3)*64 + (p >> 2);          // orig row of W0cat: gate*64 + hidden
    int kbase = kt*32 + (lane >> 4)*8;
    #pragma unroll
    for (int j = 0; j < 8; ++j) {
      int k = kbase + j; float w = 0.0f;
      if (k < 12) w = Wih0[col*12 + k];
      else if (k < 76) w = Whh0[col*64 + (k-12)];
      wh[tid*8 + j] = (_Float16)w;
    }
  } else if (tid < WF0_H8 + WF1_H8) {
    int t2 = tid - WF0_H8;
    int lane = t2 & 63; int kt = (t2 >> 6) % 6; int ct = t2 / (64*6);
    int p = ct*16 + (lane & 15);
    int col = (p & 3)*128 + (p >> 2);         // gate*128 + hidden
    int kbase = kt*32 + (lane >> 4)*8;
    #pragma unroll
    for (int j = 0; j < 8; ++j) {
      int k = kbase + j;
      float w = (k < 64) ? Wih1[col*64 + k] : Whh1[col*128 + (k-64)];
      wh[WF0_H8*8 + t2*8 + j] = (_Float16)w;
    }
  } else if (tid < WF0_H8 + WF1_H8 + 768) {
    int t3 = tid - (WF0_H8 + WF1_H8);
    if (t3 < 256) { int col = (t3 & 3)*64 + (t3 >> 2);  bs[t3] = bih0[col] + bhh0[col]; }
    else { int p1 = t3 - 256; int col = (p1 & 3)*128 + (p1 >> 2); bs[t3] = bih1[col] + bhh1[col]; }
  }
}

// ---------------------------------------------------------------------------
// Main kernel: 1024 threads (16 waves), 16 rows/block, 1024 blocks.
// st0[2][16][128]h: per row, logical [x12|h0 64|zeros], XOR-swizzled blocks.
// st1[16][512]h:    per row, logical [h0_p0 64|h0_p1 64|h1_p0 128|h1_p1 128].
// ---------------------------------------------------------------------------
__global__ __launch_bounds__(1024, 1)
void lstm_kernel(const float* __restrict__ x, const _Float16* __restrict__ wh,
                 const float* __restrict__ bs,
                 const float* __restrict__ Wd1, const float* __restrict__ bd1,
                 const float* __restrict__ Wd2, const float* __restrict__ bd2,
                 float* __restrict__ out) {
  __shared__ __align__(16) _Float16 st0[2*R*128];   // 8192 B
  __shared__ __align__(16) _Float16 st1[R*512];     // 16384 B
  __shared__ float hbuf[R*132];                     // 8448 B
  __shared__ float red[R*65];                       // 4160 B  -> ~37 KB

  const int tid  = threadIdx.x;
  const int w    = tid >> 6;
  const int lane = tid & 63;
  const int l15  = lane & 15;
  const int lg   = lane >> 4;            // 0..3
  const int a    = l15 >> 2;
  const int g    = l15 & 3;
  const int r    = lg*4 + g;             // this lane's cell batch-row
  const int rowbase = blockIdx.x * R;

  // Swizzled address helpers (addresses in halves).
  auto st0a = [](int buf, int row, int blk){          // 8-half block base
    return (buf*R + row)*128 + (((blk ^ (row & 7)) << 3)); };
  auto st0s = [](int buf, int row, int idx){          // scalar half
    return (buf*R + row)*128 + ((((idx >> 3) ^ (row & 7)) << 3) | (idx & 7)); };
  auto st1a = [](int row, int blk){
    return row*512 + (((blk ^ (row & 7)) << 3)); };
  auto st1s = [](int row, int idx){
    return row*512 + ((((idx >> 3) ^ (row & 7)) << 3) | (idx & 7)); };

  // ---- weights -> registers (AGPR-parked), pinned across the T loop ----
  const intx4* whi = (const intx4*)wh;
  intx4 wb0i[3];
  #pragma unroll
  for (int kt = 0; kt < 3; ++kt) wb0i[kt] = whi[(w*3 + kt)*64 + lane];
  intx4 wb1i[2][6];
  #pragma unroll
  for (int i = 0; i < 2; ++i)
    #pragma unroll
    for (int kt = 0; kt < 6; ++kt) wb1i[i][kt] = whi[WF0_H8 + ((2*w+i)*6 + kt)*64 + lane];
  float b0 = bs[w*16 + l15];
  float b1[2];
  #pragma unroll
  for (int i = 0; i < 2; ++i) b1[i] = bs[256 + (2*w+i)*16 + l15];

  float c0 = 0.0f, c1a = 0.0f, c1b = 0.0f;
  const int h0i = 4*w + a;
  const int h1a = 8*w + a;
  const int h1b = 8*w + 4 + a;

  // ---- zero-init LDS ----
  for (int i = tid; i < (2*R*128)/2; i += 1024) ((int*)st0)[i] = 0;
  for (int i = tid; i < (R*512)/2;   i += 1024) ((int*)st1)[i] = 0;
  __syncthreads();
  const int xr = tid / 3, xq = tid % 3;
  if (tid < 48) {
    float4 v0 = *(const float4*)&x[((size_t)(rowbase + xr)*T_STEPS + 0)*F_IN + xq*4];
    float4 v1 = *(const float4*)&x[((size_t)(rowbase + xr)*T_STEPS + 1)*F_IN + xq*4];
    half4 h40 = {(_Float16)v0.x, (_Float16)v0.y, (_Float16)v0.z, (_Float16)v0.w};
    half4 h41 = {(_Float16)v1.x, (_Float16)v1.y, (_Float16)v1.z, (_Float16)v1.w};
    *(half4*)&st0[st0s(0, xr, xq*4)] = h40;
    *(half4*)&st0[st0s(1, xr, xq*4)] = h41;
  }
  __syncthreads();

  // ---- layer-0 step: gates0(tt) from st0[tt&1]; h0(tt) -> st0[tt&1 ^1], st1[h0 parity tt&1]
  auto do_A = [&](int tt){
    const int pr = tt & 1;
    floatx4 acc = {b0, b0, b0, b0};
    #pragma unroll
    for (int kt = 0; kt < 3; ++kt) {
      half8 af = *(const half8*)&st0[st0a(pr, l15, kt*4 + lg)];
      acc = __builtin_amdgcn_mfma_f32_16x16x32_f16(af, __builtin_bit_cast(half8, wb0i[kt]), acc, 0, 0, 0);
    }
    floatx4 d = qtrans4(acc, g);
    c0 = fmaf(sigf(d[1]), c0, sigf(d[0]) * tanhf_(d[2]));
    float h0v = sigf(d[3]) * tanhf_(c0);
    _Float16 hh = (_Float16)h0v;
    st0[st0s(pr^1, r, 12 + h0i)] = hh;
    st1[st1s(r, pr*64 + h0i)]    = hh;
  };

  // ---- layer-1 step: gates1(tt) from [h0 parity tt&1 | h1 parity tt&1 ^1]; h1(tt)->parity tt&1
  auto do_C = [&](int tt){
    const int pr = tt & 1;
    floatx4 a0 = {b1[0], b1[0], b1[0], b1[0]};
    floatx4 a1 = {b1[1], b1[1], b1[1], b1[1]};
    #pragma unroll
    for (int kt = 0; kt < 6; ++kt) {
      const int blk = (kt < 2) ? (pr*8 + kt*4 + lg)
                               : (16 + (pr^1)*16 + (kt-2)*4 + lg);
      half8 af = *(const half8*)&st1[st1a(l15, blk)];
      a0 = __builtin_amdgcn_mfma_f32_16x16x32_f16(af, __builtin_bit_cast(half8, wb1i[0][kt]), a0, 0, 0, 0);
      a1 = __builtin_amdgcn_mfma_f32_16x16x32_f16(af, __builtin_bit_cast(half8, wb1i[1][kt]), a1, 0, 0, 0);
    }
    floatx4 da = qtrans4(a0, g);
    floatx4 db = qtrans4(a1, g);
    c1a = fmaf(sigf(da[1]), c1a, sigf(da[0]) * tanhf_(da[2]));
    c1b = fmaf(sigf(db[1]), c1b, sigf(db[0]) * tanhf_(db[2]));
    float h1v0 = sigf(da[3]) * tanhf_(c1a);
    float h1v1 = sigf(db[3]) * tanhf_(c1b);
    st1[st1s(r, 128 + pr*128 + h1a)] = (_Float16)h1v0;
    st1[st1s(r, 128 + pr*128 + h1b)] = (_Float16)h1v1;
    if (tt == T_STEPS - 1) { hbuf[r*132 + h1a] = h1v0; hbuf[r*132 + h1b] = h1v1; }
  };

  // ---- prologue: A(0) alone, then phases {C(t), A(t+1)} with ONE barrier ----
  do_A(0);
  __syncthreads();

  for (int t = 0; t < T_STEPS; t += 2) {
    // Pin weights: forbid remat; values stay in the unified RF.
    #pragma unroll
    for (int kt = 0; kt < 3; ++kt) asm volatile("" : "+v"(wb0i[kt]));
    #pragma unroll
    for (int i = 0; i < 2; ++i)
      #pragma unroll
      for (int kt = 0; kt < 6; ++kt) asm volatile("" : "+v"(wb1i[i][kt]));
    asm volatile("" : "+v"(b0), "+v"(b1[0]), "+v"(b1[1]));

    #pragma unroll
    for (int hl = 0; hl < 2; ++hl) {
      const int tt = t + hl;
      const int pr = hl;               // tt & 1
      // issue x(tt+2) prefetch early (lands in st0[pr] for A(tt+2))
      float4 xv = {0.0f, 0.0f, 0.0f, 0.0f};
      const bool dopre = (tt + 2 < T_STEPS);
      if (tid < 48 && dopre)
        xv = *(const float4*)&x[((size_t)(rowbase + xr)*T_STEPS + (tt+2))*F_IN + xq*4];

      do_C(tt);                        // layer1 step t
      if (tt + 1 < T_STEPS) do_A(tt+1);// layer0 step t+1 (independent of C(t))

      if (tid < 48 && dopre) {
        half4 h4 = {(_Float16)xv.x, (_Float16)xv.y, (_Float16)xv.z, (_Float16)xv.w};
        *(half4*)&st0[st0s(pr, xr, xq*4)] = h4;
      }
      __syncthreads();
    }
  }

  // ---------- Head: out[r] = b_d2 + Wd2 @ (b_d1 + Wd1 @ h1[r]) ----------
  {
    int hr = tid & 15, jg = tid >> 4;    // 64 j-groups of 2
    float partial = 0.0f;
    #pragma unroll
    for (int jj = 0; jj < 2; ++jj) {
      int j = jg*2 + jj;
      float dacc = bd1[j];
      const float4* wrow = (const float4*)&Wd1[j*128];
      #pragma unroll 8
      for (int k4 = 0; k4 < 32; ++k4) {
        float4 wv = wrow[k4];
        const float4 hv = *(const float4*)&hbuf[hr*132 + k4*4];
        dacc = fmaf(wv.x, hv.x, dacc); dacc = fmaf(wv.y, hv.y, dacc);
        dacc = fmaf(wv.z, hv.z, dacc); dacc = fmaf(wv.w, hv.w, dacc);
      }
      partial = fmaf(Wd2[j], dacc, partial);
    }
    red[hr*65 + jg] = partial;
  }
  __syncthreads();
  if (tid < R) {
    float ssum = bd2[0];
    #pragma unroll
    for (int k = 0; k < 64; ++k) ssum += red[tid*65 + k];
    out[rowbase + tid] = ssum;
  }
}

extern "C" void kernel_launch(void* const* d_in, const int* in_sizes, int n_in,
                              void* d_out, int out_size, void* d_ws, size_t ws_size,
                              hipStream_t stream) {
  const float* x    = (const float*)d_in[0];
  const float* Wih0 = (const float*)d_in[1];
  const float* Whh0 = (const float*)d_in[2];
  const float* bih0 = (const float*)d_in[3];
  const float* bhh0 = (const float*)d_in[4];
  const float* Wih1 = (const float*)d_in[5];
  const float* Whh1 = (const float*)d_in[6];
  const float* bih1 = (const float*)d_in[7];
  const float* bhh1 = (const float*)d_in[8];
  const float* Wd1  = (const float*)d_in[9];
  const float* bd1  = (const float*)d_in[10];
  const float* Wd2  = (const float*)d_in[11];
  const float* bd2  = (const float*)d_in[12];
  float* out = (float*)d_out;

  _Float16* wh  = (_Float16*)d_ws;
  float*    bsv = (float*)((char*)d_ws + (size_t)WH_TOTAL_HALVES * 2);

  prep_kernel<<<63, 256, 0, stream>>>(Wih0, Whh0, bih0, bhh0, Wih1, Whh1, bih1, bhh1, wh, bsv);
  lstm_kernel<<<1024, 1024, 0, stream>>>(x, wh, bsv, Wd1, bd1, Wd2, bd2, out);
}